// Round 1
// baseline (503.386 us; speedup 1.0000x reference)
//
#include <hip/hip_runtime.h>

#define CI    32
#define IH    224
#define IW    224
#define OHS   220
#define OWS   220
#define NF    64
#define KS    5
#define XCOLS 228
#define CP    36                 // c padding for x LDS (conflict-spread, b64 reads)  [fallback]
#define WPD   40                 // c padding for w LDS (b128-friendly)
#define XROWS 8                  // staged input rows per block (fallback path)
#define NBUFW (KS * NF * WPD)

typedef __attribute__((ext_vector_type(4))) float   f32x4;
typedef __attribute__((ext_vector_type(4))) __bf16  bf16x4;
typedef __attribute__((ext_vector_type(8))) __bf16  bf16x8;

// Repack weights fp32 [f][c][kh][kw] -> bf16 [tap=kh*5+kw][f][c] in d_ws.
__global__ void repack_w_kernel(const float* __restrict__ w, __bf16* __restrict__ wp) {
  int i = blockIdx.x * 256 + threadIdx.x;
  if (i >= KS * KS * NF * CI) return;
  int c   = i & (CI - 1);
  int f   = (i >> 5) & (NF - 1);
  int tap = i >> 11;
  int kh = tap / KS, kw = tap % KS;
  wp[i] = (__bf16)w[((f * CI + c) * KS + kh) * KS + kw];
}

// x fp32 NCHW -> bf16 NHWC ([n][h][w][c]) in d_ws. Writes fully coalesced
// (consecutive chunks -> consecutive 16B); reads 64B-segment coalesced per c-plane.
__global__ __launch_bounds__(256)
void x_transform(const float* __restrict__ x, __bf16* __restrict__ xh) {
  int chunk = blockIdx.x * 256 + threadIdx.x;   // 16*224*224*4 chunks of 8 channels
  int c8  = (chunk & 3) * 8;
  int pos = chunk >> 2;                         // n*50176 + h*224 + w
  int w   = pos % IW;
  int nh  = pos / IW;
  int n   = nh / IH;
  int h   = nh - n * IH;
  const float* xp = x + ((size_t)n * CI + c8) * (IH * IW) + h * IW + w;
  bf16x8 v;
#pragma unroll
  for (int j = 0; j < 8; ++j) v[j] = (__bf16)xp[(size_t)j * (IH * IW)];
  *(bf16x8*)(xh + (size_t)pos * CI + c8) = v;
}

// Direct-global conv: B fragments (x) loaded straight from NHWC bf16 global
// (L1-served kw-reuse), weights per-kh in a small LDS buffer. One wave = one
// (n, oh, half-row of 7x16 px) x all 64 filters. No x LDS -> 3 blocks/CU.
__global__ __launch_bounds__(256, 3)
void conv_direct(const __bf16* __restrict__ xh, const __bf16* __restrict__ wp,
                 const float* __restrict__ bias, float* __restrict__ out) {
  __shared__ __bf16 wsm[KS * NF * WPD];   // 12800 elems = 25600 B

  const int tid  = threadIdx.x;
  const int lane = tid & 63;
  const int wv   = tid >> 6;    // 0..3
  const int m    = lane & 15;   // MFMA col (pixel) / A row (filter)
  const int q    = lane >> 4;   // c-chunk / C row group

  const int bid  = blockIdx.x;
  const int lid  = (bid & 7) * 220 + (bid >> 3);  // bijection on [0,1760): XCD k -> 2 images
  const int task = lid * 4 + wv;                  // [0, 7040)
  const int n    = task / 440;
  const int r    = task - n * 440;
  const int oh   = r >> 1;
  const int ow0  = (r & 1) * 112;

  // per-lane x base: pixel (oh, ow0+m), channels q*8..q*8+7
  const __bf16* xb = xh + (((size_t)n * IH + oh) * IW + ow0 + m) * CI + q * 8;

  f32x4 acc[28];
#pragma unroll
  for (int i = 0; i < 28; ++i) { f32x4 z = {0.f, 0.f, 0.f, 0.f}; acc[i] = z; }

  for (int kh = 0; kh < KS; ++kh) {
    // stage this kh's weights [kw][f][c] into LDS (coalesced 16B global reads)
    if (kh) __syncthreads();          // all waves done reading previous kh
#pragma unroll
    for (int it = 0; it < 5; ++it) {
      int i  = it * 256 + tid;        // 0..1279
      int c0 = (i & 3) * 8;
      int f  = (i >> 2) & 63;
      int kw = i >> 8;
      *(bf16x8*)&wsm[(kw * NF + f) * WPD + c0] =
          *(const bf16x8*)(wp + (((size_t)kh * KS + kw) * NF + f) * CI + c0);
    }
    __syncthreads();

    const __bf16* xr = xb + (size_t)kh * (IW * CI);
#pragma unroll
    for (int kw = 0; kw < KS; ++kw) {
      bf16x8 af[4];
#pragma unroll
      for (int ft = 0; ft < 4; ++ft)
        af[ft] = *(const bf16x8*)&wsm[(kw * NF + ft * 16 + m) * WPD + q * 8];
#pragma unroll
      for (int j = 0; j < 7; ++j) {
        bf16x8 bv = *(const bf16x8*)(xr + (j * 16 + kw) * CI);  // 1KB coalesced/wave
#pragma unroll
        for (int ft = 0; ft < 4; ++ft)
          acc[j * 4 + ft] =
              __builtin_amdgcn_mfma_f32_16x16x32_bf16(af[ft], bv, acc[j * 4 + ft], 0, 0, 0);
      }
    }
  }

  // epilogue: C/D layout col=lane&15 (pixel), row=q*4+reg (filter within 16)
  float bvv[16];
#pragma unroll
  for (int ft = 0; ft < 4; ++ft)
#pragma unroll
    for (int rg = 0; rg < 4; ++rg)
      bvv[ft * 4 + rg] = bias[ft * 16 + q * 4 + rg];

#pragma unroll
  for (int j = 0; j < 7; ++j) {
    int ow = ow0 + j * 16 + m;
    if (ow < OWS) {
#pragma unroll
      for (int ft = 0; ft < 4; ++ft)
#pragma unroll
        for (int rg = 0; rg < 4; ++rg) {
          int f = ft * 16 + q * 4 + rg;
          out[(((size_t)n * NF + f) * OHS + oh) * OWS + ow] = acc[j * 4 + ft][rg] + bvv[ft * 4 + rg];
        }
    }
  }
}

// ---------------- fallback (previous proven kernel, used only if ws too small) ----
template <bool USE_WS>
__global__ __launch_bounds__(512, 1)
void conv_main(const float* __restrict__ x, const float* __restrict__ w,
               const __bf16* __restrict__ wp, const float* __restrict__ bias,
               float* __restrict__ out) {
  __shared__ __bf16 xs[XROWS * XCOLS * CP];
  __shared__ __bf16 wsm[NBUFW];

  const int tid  = threadIdx.x;
  const int lane = tid & 63;
  const int wv   = tid >> 6;
  const int m    = lane & 15;
  const int q    = lane >> 4;

  int bid = blockIdx.x;
  int lid = (bid >> 3) + (bid & 7) * 110;
  const int n   = lid / 55;
  const int oh0 = (lid % 55) * 4;

  {
    const float* xn = x + (size_t)n * CI * IH * IW;
    for (int p = tid; p < XROWS * 56 * 8; p += 512) {
      int pc   = p & 7;
      int pg   = p >> 3;
      int pcol = pg % 56;
      int prow = pg / 56;
      int row  = oh0 + prow;
      f32x4 v0 = *(const f32x4*)(xn + ((size_t)(pc * 4 + 0) * IH + row) * IW + pcol * 4);
      f32x4 v1 = *(const f32x4*)(xn + ((size_t)(pc * 4 + 1) * IH + row) * IW + pcol * 4);
      f32x4 v2 = *(const f32x4*)(xn + ((size_t)(pc * 4 + 2) * IH + row) * IW + pcol * 4);
      f32x4 v3 = *(const f32x4*)(xn + ((size_t)(pc * 4 + 3) * IH + row) * IW + pcol * 4);
#pragma unroll
      for (int dcol = 0; dcol < 4; ++dcol) {
        bf16x4 t;
        t[0] = (__bf16)v0[dcol]; t[1] = (__bf16)v1[dcol];
        t[2] = (__bf16)v2[dcol]; t[3] = (__bf16)v3[dcol];
        *(bf16x4*)&xs[(prow * XCOLS + pcol * 4 + dcol) * CP + pc * 4] = t;
      }
    }
    for (int z = tid; z < XROWS * 4 * CP; z += 512) {
      int rr  = z / (4 * CP);
      int rem = z - rr * (4 * CP);
      xs[(rr * XCOLS + 224) * CP + rem] = (__bf16)0.0f;
    }
  }

  if (USE_WS) {
    for (int i = tid; i < NF * CI * KS / 8; i += 512) {
      int c0 = (i & 3) * 8;
      int f  = (i >> 2) & 63;
      int kw = i >> 8;
      bf16x8 v = *(const bf16x8*)(wp + ((size_t)(0 * KS + kw) * NF + f) * CI + c0);
      *(bf16x8*)&wsm[(kw * NF + f) * WPD + c0] = v;
    }
  } else {
    for (int i = tid; i < KS * NF * CI; i += 512) {
      int c  = i & 31;
      int f  = (i >> 5) & 63;
      int kw = i >> 11;
      wsm[(kw * NF + f) * WPD + c] = (__bf16)w[((f * CI + c) * KS + 0) * KS + kw];
    }
  }
  __syncthreads();

  int rj[7], cbj[7], xoff[7];
#pragma unroll
  for (int j = 0; j < 7; ++j) {
    int t   = wv + j * 8;
    rj[j]   = t / 14;
    cbj[j]  = (t % 14) * 16;
    xoff[j] = (rj[j] * XCOLS + cbj[j] + m) * CP + q * 8;
  }

  f32x4 acc[28];
#pragma unroll
  for (int i = 0; i < 28; ++i) { f32x4 z = {0.f, 0.f, 0.f, 0.f}; acc[i] = z; }

  for (int kh = 0; kh < KS; ++kh) {
    bf16x8 pw[3];
    if (USE_WS && kh < KS - 1) {
#pragma unroll
      for (int it = 0; it < 3; ++it) {
        int e = it * 512 + tid;
        if (e < 1280) {
          int c0 = (e & 3) * 8;
          int f  = (e >> 2) & 63;
          int kw = e >> 8;
          pw[it] = *(const bf16x8*)(wp + ((size_t)((kh + 1) * KS + kw) * NF + f) * CI + c0);
        }
      }
    }

#pragma unroll
    for (int kw = 0; kw < KS; ++kw) {
      bf16x8 af[4];
#pragma unroll
      for (int ft = 0; ft < 4; ++ft)
        af[ft] = *(const bf16x8*)&wsm[(kw * NF + ft * 16 + m) * WPD + q * 8];
#pragma unroll
      for (int j = 0; j < 7; ++j) {
        const __bf16* bp = &xs[xoff[j] + (kh * XCOLS + kw) * CP];
        bf16x4 lo = *(const bf16x4*)bp;
        bf16x4 hi = *(const bf16x4*)(bp + 4);
        bf16x8 bv8 = __builtin_shufflevector(lo, hi, 0, 1, 2, 3, 4, 5, 6, 7);
#pragma unroll
        for (int ft = 0; ft < 4; ++ft)
          acc[j * 4 + ft] =
              __builtin_amdgcn_mfma_f32_16x16x32_bf16(af[ft], bv8, acc[j * 4 + ft], 0, 0, 0);
      }
    }

    if (kh < KS - 1) {
      __syncthreads();
      if (USE_WS) {
#pragma unroll
        for (int it = 0; it < 3; ++it) {
          int e = it * 512 + tid;
          if (e < 1280) {
            int c0 = (e & 3) * 8;
            int f  = (e >> 2) & 63;
            int kw = e >> 8;
            *(bf16x8*)&wsm[(kw * NF + f) * WPD + c0] = pw[it];
          }
        }
      } else {
        for (int i = tid; i < KS * NF * CI; i += 512) {
          int c  = i & 31;
          int f  = (i >> 5) & 63;
          int kw = i >> 11;
          wsm[(kw * NF + f) * WPD + c] =
              (__bf16)w[((f * CI + c) * KS + (kh + 1)) * KS + kw];
        }
      }
      __syncthreads();
    }
  }

  float bvv[16];
#pragma unroll
  for (int ft = 0; ft < 4; ++ft)
#pragma unroll
    for (int rg = 0; rg < 4; ++rg)
      bvv[ft * 4 + rg] = bias[ft * 16 + q * 4 + rg];

#pragma unroll
  for (int j = 0; j < 7; ++j) {
    int ow = cbj[j] + m;
    if (ow < OWS) {
      int oh = oh0 + rj[j];
#pragma unroll
      for (int ft = 0; ft < 4; ++ft) {
#pragma unroll
        for (int rg = 0; rg < 4; ++rg) {
          int f = ft * 16 + q * 4 + rg;
          out[(((size_t)n * NF + f) * OHS + oh) * OWS + ow] = acc[j * 4 + ft][rg] + bvv[ft * 4 + rg];
        }
      }
    }
  }
}

extern "C" void kernel_launch(void* const* d_in, const int* in_sizes, int n_in,
                              void* d_out, int out_size, void* d_ws, size_t ws_size,
                              hipStream_t stream) {
  const float* x    = (const float*)d_in[0];
  const float* w    = (const float*)d_in[1];
  const float* bias = (const float*)d_in[2];
  float* out = (float*)d_out;

  const int    NW = KS * KS * NF * CI;                              // 51200
  const size_t WB = (size_t)NW * sizeof(__bf16);                    // 102400 B
  const size_t XB = (size_t)16 * IH * IW * CI * sizeof(__bf16);     // 51,380,224 B

  if (ws_size >= WB + XB + 256) {
    // fast path: repacked weights + NHWC bf16 x in workspace (256B tail slack
    // absorbs masked-column OOB reads at the row tail)
    __bf16* wp  = (__bf16*)d_ws;
    __bf16* xhp = (__bf16*)((char*)d_ws + WB);
    repack_w_kernel<<<(NW + 255) / 256, 256, 0, stream>>>(w, wp);
    x_transform<<<(16 * IH * IW * 4) / 256, 256, 0, stream>>>(x, xhp);
    conv_direct<<<1760, 256, 0, stream>>>(xhp, wp, bias, out);
  } else if (ws_size >= WB) {
    __bf16* wp = (__bf16*)d_ws;
    repack_w_kernel<<<(NW + 255) / 256, 256, 0, stream>>>(w, wp);
    conv_main<true><<<880, 512, 0, stream>>>(x, w, wp, bias, out);
  } else {
    conv_main<false><<<880, 512, 0, stream>>>(x, w, nullptr, bias, out);
  }
}

// Round 2
// 360.407 us; speedup vs baseline: 1.3967x; 1.3967x over previous
//
#include <hip/hip_runtime.h>

#define CI    32
#define IH    224
#define IW    224
#define OHS   220
#define OWS   220
#define NF    64
#define KS    5

// fallback-kernel macros
#define XCOLS 228
#define CP    36
#define WPD   40
#define XROWS 8
#define NBUFW (KS * NF * WPD)

// conv_lds staged x tile: 8 rows x 116 px x 32 c bf16, flat 16B chunks
#define PXW   116
#define RCHK  (PXW * 4)          // 464 chunks per row
#define NROWS 8
#define TCHK  (RCHK * NROWS)     // 3712 chunks = 58 wave-instrs of 64
#define ROWB  (RCHK * 16)        // 7424 B per staged row

typedef __attribute__((ext_vector_type(4))) float   f32x4;
typedef __attribute__((ext_vector_type(4))) __bf16  bf16x4;
typedef __attribute__((ext_vector_type(8))) __bf16  bf16x8;

// Repack weights fp32 [f][c][kh][kw] -> bf16 [tap=kh*5+kw][f][c].
__global__ void repack_w_kernel(const float* __restrict__ w, __bf16* __restrict__ wp) {
  int i = blockIdx.x * 256 + threadIdx.x;
  if (i >= KS * KS * NF * CI) return;
  int c   = i & (CI - 1);
  int f   = (i >> 5) & (NF - 1);
  int tap = i >> 11;
  int kh = tap / KS, kw = tap % KS;
  wp[i] = (__bf16)w[((f * CI + c) * KS + kh) * KS + kw];
}

// x fp32 NCHW -> bf16 NHWC ([n][h][w][c]).
__global__ __launch_bounds__(256)
void x_transform(const float* __restrict__ x, __bf16* __restrict__ xh) {
  int chunk = blockIdx.x * 256 + threadIdx.x;   // 16*224*224*4 chunks of 8 channels
  int c8  = (chunk & 3) * 8;
  int pos = chunk >> 2;                         // n*50176 + h*224 + w
  int w   = pos % IW;
  int nh  = pos / IW;
  int n   = nh / IH;
  int h   = nh - n * IH;
  const float* xp = x + ((size_t)n * CI + c8) * (IH * IW) + h * IW + w;
  bf16x8 v;
#pragma unroll
  for (int j = 0; j < 8; ++j) v[j] = (__bf16)xp[(size_t)j * (IH * IW)];
  *(bf16x8*)(xh + (size_t)pos * CI + c8) = v;
}

// LDS-staged conv from NHWC bf16: one-shot global_load_lds stage (XOR-swizzled
// chunks), weights direct from global (L1-resident), zero k-loop barriers.
// Block = 256 thr (4 waves), tile = 4 oh x 112 ow x 64 f; wave = 7 px-tiles x 64 f.
__global__ __launch_bounds__(256, 2)
void conv_lds(const __bf16* __restrict__ xh, const __bf16* __restrict__ wp,
              const float* __restrict__ bias, float* __restrict__ out) {
  __shared__ __bf16 xs[TCHK * 8];   // 59392 B, flat: [row r][chunk' 0..463] 16B chunks

  const int tid  = threadIdx.x;
  const int lane = tid & 63;
  const int wv   = tid >> 6;    // 0..3
  const int m    = lane & 15;   // MFMA col (pixel) / A row (filter)
  const int q    = lane >> 4;   // c-chunk / C row group

  const int bid = blockIdx.x;
  const int lid = (bid & 7) * 220 + (bid >> 3);  // bijection on [0,1760): XCD k -> 2 images
  const int n   = lid / 110;
  const int rem = lid - n * 110;
  const int oh0 = (rem >> 1) * 4;                // 0..216
  const int ow0 = (rem & 1) * 112;

  // ---- one-shot stage: rows oh0..oh0+7, px [ow0, ow0+116) ----
  // LDS chunk L holds global chunk sigma(L%464) of row L/464, sigma(c)=c^((c>>3)&3)
  // (involution). ow0=112 tail px 224..227 reads next row / wp region: feeds only
  // masked ow>=220 columns.
  {
    const __bf16* xb = xh + (((size_t)n * IH + oh0) * IW + ow0) * CI;
    for (int i = wv; i < TCHK / 64; i += 4) {
      int L  = i * 64 + lane;
      int r  = L / RCHK;
      int cr = L - r * RCHK;
      int cs = cr ^ ((cr >> 3) & 3);
      const __bf16* src = xb + (size_t)r * (IW * CI) + cs * 8;
      __builtin_amdgcn_global_load_lds(
          (const __attribute__((address_space(1))) void*)src,
          (__attribute__((address_space(3))) void*)&xs[i * 512], 16, 0, 0);
    }
  }

  // per-wave tile geometry + swizzled LDS byte offsets (static reg array)
  int cj[7], rjv[7];
  int boff[7][5];
#pragma unroll
  for (int j = 0; j < 7; ++j) {
    int t  = wv + j * 4;          // 0..27
    int rj = t / 7;               // output row offset 0..3
    rjv[j] = rj;
    cj[j]  = (t - rj * 7) * 16;   // px-tile base 0..96
#pragma unroll
    for (int kw = 0; kw < KS; ++kw) {
      int g = (cj[j] + kw + m) * 4 + q;       // linear chunk within row
      int s = g ^ ((g >> 3) & 3);             // swizzled
      boff[j][kw] = rj * ROWB + s * 16;       // byte offset for kh=0
    }
  }

  f32x4 acc[28];
#pragma unroll
  for (int i = 0; i < 28; ++i) { f32x4 z = {0.f, 0.f, 0.f, 0.f}; acc[i] = z; }

  const __bf16* wpl = wp + m * CI + q * 8;    // lane base into [tap][f][c]

  __syncthreads();

  for (int kh = 0; kh < KS; ++kh) {
    const int khb = kh * ROWB;
#pragma unroll
    for (int kw = 0; kw < KS; ++kw) {
      const int tap = kh * KS + kw;
      bf16x8 af[4];
#pragma unroll
      for (int ft = 0; ft < 4; ++ft)          // 1KB/wave coalesced, L1-resident
        af[ft] = *(const bf16x8*)(wpl + (size_t)tap * (NF * CI) + ft * 16 * CI);
#pragma unroll
      for (int j = 0; j < 7; ++j) {
        bf16x8 bv = *(const bf16x8*)((const char*)xs + khb + boff[j][kw]);
#pragma unroll
        for (int ft = 0; ft < 4; ++ft)
          acc[j * 4 + ft] =
              __builtin_amdgcn_mfma_f32_16x16x32_bf16(af[ft], bv, acc[j * 4 + ft], 0, 0, 0);
      }
    }
  }

  // epilogue: C/D layout col=lane&15 (pixel), row=q*4+reg (filter within 16)
  float bvv[16];
#pragma unroll
  for (int ft = 0; ft < 4; ++ft)
#pragma unroll
    for (int rg = 0; rg < 4; ++rg)
      bvv[ft * 4 + rg] = bias[ft * 16 + q * 4 + rg];

#pragma unroll
  for (int j = 0; j < 7; ++j) {
    int ow = ow0 + cj[j] + m;
    if (ow < OWS) {
      int oh = oh0 + rjv[j];
#pragma unroll
      for (int ft = 0; ft < 4; ++ft)
#pragma unroll
        for (int rg = 0; rg < 4; ++rg) {
          int f = ft * 16 + q * 4 + rg;
          out[(((size_t)n * NF + f) * OHS + oh) * OWS + ow] = acc[j * 4 + ft][rg] + bvv[ft * 4 + rg];
        }
    }
  }
}

// ---------------- fallback (proven kernel, used only if ws too small) ----
template <bool USE_WS>
__global__ __launch_bounds__(512, 1)
void conv_main(const float* __restrict__ x, const float* __restrict__ w,
               const __bf16* __restrict__ wp, const float* __restrict__ bias,
               float* __restrict__ out) {
  __shared__ __bf16 xs[XROWS * XCOLS * CP];
  __shared__ __bf16 wsm[NBUFW];

  const int tid  = threadIdx.x;
  const int lane = tid & 63;
  const int wv   = tid >> 6;
  const int m    = lane & 15;
  const int q    = lane >> 4;

  int bid = blockIdx.x;
  int lid = (bid >> 3) + (bid & 7) * 110;
  const int n   = lid / 55;
  const int oh0 = (lid % 55) * 4;

  {
    const float* xn = x + (size_t)n * CI * IH * IW;
    for (int p = tid; p < XROWS * 56 * 8; p += 512) {
      int pc   = p & 7;
      int pg   = p >> 3;
      int pcol = pg % 56;
      int prow = pg / 56;
      int row  = oh0 + prow;
      f32x4 v0 = *(const f32x4*)(xn + ((size_t)(pc * 4 + 0) * IH + row) * IW + pcol * 4);
      f32x4 v1 = *(const f32x4*)(xn + ((size_t)(pc * 4 + 1) * IH + row) * IW + pcol * 4);
      f32x4 v2 = *(const f32x4*)(xn + ((size_t)(pc * 4 + 2) * IH + row) * IW + pcol * 4);
      f32x4 v3 = *(const f32x4*)(xn + ((size_t)(pc * 4 + 3) * IH + row) * IW + pcol * 4);
#pragma unroll
      for (int dcol = 0; dcol < 4; ++dcol) {
        bf16x4 t;
        t[0] = (__bf16)v0[dcol]; t[1] = (__bf16)v1[dcol];
        t[2] = (__bf16)v2[dcol]; t[3] = (__bf16)v3[dcol];
        *(bf16x4*)&xs[(prow * XCOLS + pcol * 4 + dcol) * CP + pc * 4] = t;
      }
    }
    for (int z = tid; z < XROWS * 4 * CP; z += 512) {
      int rr  = z / (4 * CP);
      int rem = z - rr * (4 * CP);
      xs[(rr * XCOLS + 224) * CP + rem] = (__bf16)0.0f;
    }
  }

  if (USE_WS) {
    for (int i = tid; i < NF * CI * KS / 8; i += 512) {
      int c0 = (i & 3) * 8;
      int f  = (i >> 2) & 63;
      int kw = i >> 8;
      bf16x8 v = *(const bf16x8*)(wp + ((size_t)(0 * KS + kw) * NF + f) * CI + c0);
      *(bf16x8*)&wsm[(kw * NF + f) * WPD + c0] = v;
    }
  } else {
    for (int i = tid; i < KS * NF * CI; i += 512) {
      int c  = i & 31;
      int f  = (i >> 5) & 63;
      int kw = i >> 11;
      wsm[(kw * NF + f) * WPD + c] = (__bf16)w[((f * CI + c) * KS + 0) * KS + kw];
    }
  }
  __syncthreads();

  int rj[7], cbj[7], xoff[7];
#pragma unroll
  for (int j = 0; j < 7; ++j) {
    int t   = wv + j * 8;
    rj[j]   = t / 14;
    cbj[j]  = (t % 14) * 16;
    xoff[j] = (rj[j] * XCOLS + cbj[j] + m) * CP + q * 8;
  }

  f32x4 acc[28];
#pragma unroll
  for (int i = 0; i < 28; ++i) { f32x4 z = {0.f, 0.f, 0.f, 0.f}; acc[i] = z; }

  for (int kh = 0; kh < KS; ++kh) {
    bf16x8 pw[3];
    if (USE_WS && kh < KS - 1) {
#pragma unroll
      for (int it = 0; it < 3; ++it) {
        int e = it * 512 + tid;
        if (e < 1280) {
          int c0 = (e & 3) * 8;
          int f  = (e >> 2) & 63;
          int kw = e >> 8;
          pw[it] = *(const bf16x8*)(wp + ((size_t)((kh + 1) * KS + kw) * NF + f) * CI + c0);
        }
      }
    }

#pragma unroll
    for (int kw = 0; kw < KS; ++kw) {
      bf16x8 af[4];
#pragma unroll
      for (int ft = 0; ft < 4; ++ft)
        af[ft] = *(const bf16x8*)&wsm[(kw * NF + ft * 16 + m) * WPD + q * 8];
#pragma unroll
      for (int j = 0; j < 7; ++j) {
        const __bf16* bp = &xs[xoff[j] + (kh * XCOLS + kw) * CP];
        bf16x4 lo = *(const bf16x4*)bp;
        bf16x4 hi = *(const bf16x4*)(bp + 4);
        bf16x8 bv8 = __builtin_shufflevector(lo, hi, 0, 1, 2, 3, 4, 5, 6, 7);
#pragma unroll
        for (int ft = 0; ft < 4; ++ft)
          acc[j * 4 + ft] =
              __builtin_amdgcn_mfma_f32_16x16x32_bf16(af[ft], bv8, acc[j * 4 + ft], 0, 0, 0);
      }
    }

    if (kh < KS - 1) {
      __syncthreads();
      if (USE_WS) {
#pragma unroll
        for (int it = 0; it < 3; ++it) {
          int e = it * 512 + tid;
          if (e < 1280) {
            int c0 = (e & 3) * 8;
            int f  = (e >> 2) & 63;
            int kw = e >> 8;
            *(bf16x8*)&wsm[(kw * NF + f) * WPD + c0] = pw[it];
          }
        }
      } else {
        for (int i = tid; i < KS * NF * CI; i += 512) {
          int c  = i & 31;
          int f  = (i >> 5) & 63;
          int kw = i >> 11;
          wsm[(kw * NF + f) * WPD + c] =
              (__bf16)w[((f * CI + c) * KS + (kh + 1)) * KS + kw];
        }
      }
      __syncthreads();
    }
  }

  float bvv[16];
#pragma unroll
  for (int ft = 0; ft < 4; ++ft)
#pragma unroll
    for (int rg = 0; rg < 4; ++rg)
      bvv[ft * 4 + rg] = bias[ft * 16 + q * 4 + rg];

#pragma unroll
  for (int j = 0; j < 7; ++j) {
    int ow = cbj[j] + m;
    if (ow < OWS) {
      int oh = oh0 + rj[j];
#pragma unroll
      for (int ft = 0; ft < 4; ++ft) {
#pragma unroll
        for (int rg = 0; rg < 4; ++rg) {
          int f = ft * 16 + q * 4 + rg;
          out[(((size_t)n * NF + f) * OHS + oh) * OWS + ow] = acc[j * 4 + ft][rg] + bvv[ft * 4 + rg];
        }
      }
    }
  }
}

extern "C" void kernel_launch(void* const* d_in, const int* in_sizes, int n_in,
                              void* d_out, int out_size, void* d_ws, size_t ws_size,
                              hipStream_t stream) {
  const float* x    = (const float*)d_in[0];
  const float* w    = (const float*)d_in[1];
  const float* bias = (const float*)d_in[2];
  float* out = (float*)d_out;

  const int    NW = KS * KS * NF * CI;                              // 51200
  const size_t WB = (size_t)NW * sizeof(__bf16);                    // 102400 B
  const size_t XB = (size_t)16 * IH * IW * CI * sizeof(__bf16);     // 51,380,224 B

  if (ws_size >= XB + WB) {
    // fast path: NHWC bf16 x first, repacked weights after it (xh tail
    // overruns from masked-column reads land harmlessly in the wp region)
    __bf16* xhp = (__bf16*)d_ws;
    __bf16* wp  = (__bf16*)((char*)d_ws + XB);
    repack_w_kernel<<<(NW + 255) / 256, 256, 0, stream>>>(w, wp);
    x_transform<<<(16 * IH * IW * 4) / 256, 256, 0, stream>>>(x, xhp);
    conv_lds<<<1760, 256, 0, stream>>>(xhp, wp, bias, out);
  } else if (ws_size >= WB) {
    __bf16* wp = (__bf16*)d_ws;
    repack_w_kernel<<<(NW + 255) / 256, 256, 0, stream>>>(w, wp);
    conv_main<true><<<880, 512, 0, stream>>>(x, w, wp, bias, out);
  } else {
    conv_main<false><<<880, 512, 0, stream>>>(x, w, nullptr, bias, out);
  }
}